// Round 3
// baseline (617.210 us; speedup 1.0000x reference)
//
#include <hip/hip_runtime.h>

#define N_   128
#define C_   12
#define L_   2048
#define D_   8
#define DIV_ 2
#define H_   32
#define K_   8
#define CP_  6
#define KW_  9
#define FEAT_ 8192   // D*DIV*2*H*K

// One block per (n, di, df, h). 256 threads, each owns 8 time positions.
__global__ __launch_bounds__(256, 4) void hydra_kernel(
    const float* __restrict__ X,   // [N, C, L]
    const float* __restrict__ W,   // [D, DIV, K*H, 1, KW]
    const int*   __restrict__ I,   // [D, DIV, H, CP]
    float* __restrict__ out)       // [N, FEAT]
{
    __shared__ float s_inp[3072];  // max Lsrc + 8*d = 2048 + 1024
    __shared__ float s_out[16];

    const int tid  = threadIdx.x;
    const int b    = blockIdx.x;
    const int h    = b & (H_ - 1);
    const int comb = (b >> 5) & 15;     // di*2 + df
    const int n    = b >> 9;
    const int df   = comb & 1;
    const int di   = comb >> 1;
    const int d    = 1 << di;
    const int Lsrc = L_ - df;           // 2048 (df=0) or 2047 (df=1)
    const int Lout = Lsrc;
    const int pad  = 4 * d;

    // zero padded staging buffer + block accumulators
    #pragma unroll
    for (int i = 0; i < 12; ++i) s_inp[tid + i * 256] = 0.0f;
    if (tid < 16) s_out[tid] = 0.0f;

    // block-uniform channel indices (scalarized by compiler)
    const int* Ib = I + (comb * H_ + h) * CP_;
    const int c0 = Ib[0], c1 = Ib[1], c2 = Ib[2],
              c3 = Ib[3], c4 = Ib[4], c5 = Ib[5];
    const float* Xn = X + (size_t)n * (C_ * L_);
    const float* x0 = Xn + c0 * L_;
    const float* x1 = Xn + c1 * L_;
    const float* x2 = Xn + c2 * L_;
    const float* x3 = Xn + c3 * L_;
    const float* x4 = Xn + c4 * L_;
    const float* x5 = Xn + c5 * L_;

    // block-uniform weights: 8 kernels x 9 taps (contiguous 72 floats)
    const float* Wb = W + (size_t)(comb * (K_ * H_) + h * K_) * KW_;
    float wreg[K_][KW_];
    #pragma unroll
    for (int k = 0; k < K_; ++k)
        #pragma unroll
        for (int w = 0; w < KW_; ++w)
            wreg[k][w] = Wb[k * KW_ + w];

    __syncthreads();  // zeros visible before overlapping fill

    // gather + sum 6 channels (diff on the fly for df=1)
    for (int t = tid; t < Lsrc; t += 256) {
        float v;
        if (df == 0) {
            v = x0[t] + x1[t] + x2[t] + x3[t] + x4[t] + x5[t];
        } else {
            v = (x0[t + 1] - x0[t]) + (x1[t + 1] - x1[t]) + (x2[t + 1] - x2[t])
              + (x3[t + 1] - x3[t]) + (x4[t + 1] - x4[t]) + (x5[t + 1] - x5[t]);
        }
        s_inp[pad + t] = v;
    }

    __syncthreads();

    float cx[K_] = {0.f, 0.f, 0.f, 0.f, 0.f, 0.f, 0.f, 0.f};
    float cn[K_] = {0.f, 0.f, 0.f, 0.f, 0.f, 0.f, 0.f, 0.f};

    #pragma unroll
    for (int i = 0; i < 8; ++i) {
        const int t = tid + i * 256;
        if (t < Lout) {
            float acc[K_] = {0.f, 0.f, 0.f, 0.f, 0.f, 0.f, 0.f, 0.f};
            #pragma unroll
            for (int w = 0; w < KW_; ++w) {
                const float v = s_inp[t + w * d];   // stride-1 across lanes: conflict-free
                #pragma unroll
                for (int k = 0; k < K_; ++k)
                    acc[k] = fmaf(v, wreg[k][w], acc[k]);
            }
            // first-occurrence argmax/argmin (matches jnp tie-break)
            float bmax = acc[0]; int bi = 0;
            float bmin = acc[0]; int mi = 0;
            #pragma unroll
            for (int k = 1; k < K_; ++k) {
                if (acc[k] > bmax) { bmax = acc[k]; bi = k; }
                if (acc[k] < bmin) { bmin = acc[k]; mi = k; }
            }
            // static-indexed select-accumulate (no runtime-indexed local array)
            #pragma unroll
            for (int k = 0; k < K_; ++k) {
                cx[k] += (bi == k) ? bmax : 0.0f;
                cn[k] += (mi == k) ? 1.0f : 0.0f;
            }
        }
    }

    // wave (64-lane) shuffle reduction of the 16 accumulators
    #pragma unroll
    for (int k = 0; k < K_; ++k) {
        #pragma unroll
        for (int off = 32; off > 0; off >>= 1) {
            cx[k] += __shfl_down(cx[k], off, 64);
            cn[k] += __shfl_down(cn[k], off, 64);
        }
    }
    if ((tid & 63) == 0) {
        #pragma unroll
        for (int k = 0; k < K_; ++k) {
            atomicAdd(&s_out[k], cx[k]);
            atomicAdd(&s_out[8 + k], cn[k]);
        }
    }
    __syncthreads();

    if (tid < 16) {
        const int s = tid >> 3;          // 0 = cmax, 1 = cmin
        const int k = tid & 7;
        const int feat = (comb * 2 + s) * (H_ * K_) + h * K_ + k;
        out[(size_t)n * FEAT_ + feat] = s_out[tid];
    }
}

extern "C" void kernel_launch(void* const* d_in, const int* in_sizes, int n_in,
                              void* d_out, int out_size, void* d_ws, size_t ws_size,
                              hipStream_t stream) {
    const float* X = (const float*)d_in[0];
    const float* W = (const float*)d_in[1];
    const int*   I = (const int*)d_in[2];
    float* out = (float*)d_out;

    const int blocks = N_ * D_ * DIV_ * H_;   // 65536
    hipLaunchKernelGGL(hydra_kernel, dim3(blocks), dim3(256), 0, stream,
                       X, W, I, out);
}